// Round 2
// baseline (507.187 us; speedup 1.0000x reference)
//
#include <hip/hip_runtime.h>
#include <hip/hip_bf16.h>
#include <cstdint>

#define DIM   1536
#define HEADS 12
#define HD    128
#define LSEQ  3520
#define MPAD  3584
#define NKV   55
#define EPSF  1e-6f
#define SCALEF 0.08838834764831845f  // 1/sqrt(128)

typedef __attribute__((ext_vector_type(4))) float f32x4;
typedef __attribute__((ext_vector_type(8))) short bf16x8;

__device__ __forceinline__ void gload16(const void* g, void* l) {
  __builtin_amdgcn_global_load_lds(
      (const __attribute__((address_space(1))) void*)g,
      (__attribute__((address_space(3))) void*)l, 16, 0, 0);
}

__device__ __forceinline__ ushort f2bf(float f) {
  union { float f; unsigned u; } v; v.f = f;
  unsigned u = v.u;
  return (ushort)((u + 0x7FFFu + ((u >> 16) & 1u)) >> 16);
}

__device__ __forceinline__ float bf2f(ushort u) {
  union { unsigned u; float f; } v; v.u = ((unsigned)u) << 16;
  return v.f;
}

// ---------------- cast f32 -> bf16, zero-pad beyond n_valid ----------------
__global__ __launch_bounds__(256) void cast_kernel(const float* __restrict__ src,
                                                   ushort* __restrict__ dst,
                                                   long n_valid) {
  long i8 = ((long)blockIdx.x * 256 + threadIdx.x) * 8;
  bf16x8 o = (bf16x8)(short)0;
  if (i8 < n_valid) {
    float4 a = *(const float4*)(src + i8);
    float4 b = *(const float4*)(src + i8 + 4);
    o[0] = (short)f2bf(a.x); o[1] = (short)f2bf(a.y);
    o[2] = (short)f2bf(a.z); o[3] = (short)f2bf(a.w);
    o[4] = (short)f2bf(b.x); o[5] = (short)f2bf(b.y);
    o[6] = (short)f2bf(b.z); o[7] = (short)f2bf(b.w);
  }
  *(bf16x8*)(dst + i8) = o;
}

__global__ __launch_bounds__(256) void zero_tail_kernel(ushort* __restrict__ p) {
  int i = blockIdx.x * 256 + threadIdx.x;
  ((ushort4*)p)[i] = make_ushort4(0, 0, 0, 0);
}

// ---------------- GEMM: C[m][n] = sum_k A[m][k]*B[n][k]  (B is row-major N x K) ----
// MODE 1: Ct[n][m] = bf16(acc + bias[n])      (transposed bf16 -> vT)
// MODE 2: Cf[m][n] = acc + bias[n]            (fp32 to d_out, rows < LSEQ)
// MODE 3: Ct[m][n] = bf16(acc + bias[n])      (row-major bf16, rows < LSEQ)
template<int MODE>
__global__ __launch_bounds__(256) void gemm_bt(const ushort* __restrict__ A,
                                               const ushort* __restrict__ B,
                                               const float* __restrict__ bias,
                                               float* __restrict__ Cf,
                                               ushort* __restrict__ Ct) {
  __shared__ ushort As[128 * 64];
  __shared__ ushort Bs[128 * 64];
  const int m0 = blockIdx.x * 128;
  const int n0 = blockIdx.y * 128;
  const int t = threadIdx.x;
  const int lane = t & 63;
  const int w = t >> 6;
  const int wr = w >> 1, wc = w & 1;
  const int sr = t >> 3;   // 0..31
  const int sc = t & 7;    // 0..7

  f32x4 acc[4][4];
#pragma unroll
  for (int i = 0; i < 4; ++i)
#pragma unroll
    for (int j = 0; j < 4; ++j) acc[i][j] = (f32x4)0.0f;

  const int arow = 64 * wr + (lane & 15);
  const int brow = 64 * wc + (lane & 15);

  for (int k0 = 0; k0 < DIM; k0 += 64) {
    __syncthreads();
#pragma unroll
    for (int i = 0; i < 4; ++i) {
      int row = sr + 32 * i;
      int cs = sc ^ (row & 7);
      gload16(A + (long)(m0 + row) * DIM + k0 + cs * 8, (char*)As + row * 128 + sc * 16);
      gload16(B + (long)(n0 + row) * DIM + k0 + cs * 8, (char*)Bs + row * 128 + sc * 16);
    }
    __syncthreads();
    bf16x8 af[4][2], bfr[4][2];
#pragma unroll
    for (int mi = 0; mi < 4; ++mi) {
      int row = arow + 16 * mi;
#pragma unroll
      for (int ks = 0; ks < 2; ++ks) {
        int ck = (ks * 4 + (lane >> 4)) ^ (row & 7);
        af[mi][ks] = *(const bf16x8*)(As + row * 64 + ck * 8);
      }
    }
#pragma unroll
    for (int ni = 0; ni < 4; ++ni) {
      int row = brow + 16 * ni;
#pragma unroll
      for (int ks = 0; ks < 2; ++ks) {
        int ck = (ks * 4 + (lane >> 4)) ^ (row & 7);
        bfr[ni][ks] = *(const bf16x8*)(Bs + row * 64 + ck * 8);
      }
    }
#pragma unroll
    for (int mi = 0; mi < 4; ++mi)
#pragma unroll
      for (int ni = 0; ni < 4; ++ni)
#pragma unroll
        for (int ks = 0; ks < 2; ++ks)
          acc[mi][ni] = __builtin_amdgcn_mfma_f32_16x16x32_bf16(
              af[mi][ks], bfr[ni][ks], acc[mi][ni], 0, 0, 0);
  }

#pragma unroll
  for (int mi = 0; mi < 4; ++mi) {
#pragma unroll
    for (int ni = 0; ni < 4; ++ni) {
      int gmb = m0 + 64 * wr + 16 * mi + (lane >> 4) * 4;
      int gn  = n0 + 64 * wc + 16 * ni + (lane & 15);
      float bv = bias[gn];
      if (MODE == 1) {
        if (gmb < LSEQ) {
          ushort4 o;
          o.x = f2bf(acc[mi][ni][0] + bv);
          o.y = f2bf(acc[mi][ni][1] + bv);
          o.z = f2bf(acc[mi][ni][2] + bv);
          o.w = f2bf(acc[mi][ni][3] + bv);
          *(ushort4*)(Ct + (long)gn * LSEQ + gmb) = o;
        }
      } else if (MODE == 2) {
        if (gmb < LSEQ) {
#pragma unroll
          for (int j = 0; j < 4; ++j)
            Cf[(long)(gmb + j) * DIM + gn] = acc[mi][ni][j] + bv;
        }
      } else {  // MODE 3
        if (gmb < LSEQ) {
#pragma unroll
          for (int j = 0; j < 4; ++j)
            Ct[(long)(gmb + j) * DIM + gn] = f2bf(acc[mi][ni][j] + bv);
        }
      }
    }
  }
}

// -------- in-place (bf16): bias already added -> RMSNorm -> RoPE -> bf16 --------
__global__ __launch_bounds__(256) void postqk_kernel(ushort* __restrict__ qb,
    ushort* __restrict__ kb, const float* __restrict__ gq_,
    const float* __restrict__ gk_, const float* __restrict__ freqs) {
  const int l = blockIdx.x;
  const int t = threadIdx.x;
  ushort* buf      = blockIdx.y ? kb : qb;
  const float* g   = blockIdx.y ? gk_ : gq_;
  ushort* row = buf + (long)l * DIM + t * 6;
  float v[6];
  {
    ushort2 p0 = *(const ushort2*)(row);
    ushort2 p1 = *(const ushort2*)(row + 2);
    ushort2 p2 = *(const ushort2*)(row + 4);
    v[0] = bf2f(p0.x); v[1] = bf2f(p0.y); v[2] = bf2f(p1.x);
    v[3] = bf2f(p1.y); v[4] = bf2f(p2.x); v[5] = bf2f(p2.y);
  }
  float ss = v[0]*v[0] + v[1]*v[1] + v[2]*v[2] + v[3]*v[3] + v[4]*v[4] + v[5]*v[5];
#pragma unroll
  for (int off = 1; off < 64; off <<= 1) ss += __shfl_xor(ss, off);
  __shared__ float red[4];
  if ((t & 63) == 0) red[t >> 6] = ss;
  __syncthreads();
  float scale = rsqrtf((red[0] + red[1] + red[2] + red[3]) * (1.0f / DIM) + EPSF);
  const int fi = l / (22 * 40);
  const int hi = (l / 40) % 22;
  const int wi = l % 40;
  ushort o[6];
#pragma unroll
  for (int ii = 0; ii < 3; ++ii) {
    int pg = t * 3 + ii;          // global pair index
    int c = pg & 63;              // within-head pair index
    int rsel = (c < 22) ? fi : ((c < 43) ? hi : wi);
    float ang = freqs[rsel * 64 + c];
    float sn, cs;
    __sincosf(ang, &sn, &cs);
    float x0 = v[2*ii]   * scale * g[t*6 + 2*ii];
    float x1 = v[2*ii+1] * scale * g[t*6 + 2*ii+1];
    o[2*ii]   = f2bf(x0 * cs - x1 * sn);
    o[2*ii+1] = f2bf(x0 * sn + x1 * cs);
  }
  *(ushort2*)(row)     = make_ushort2(o[0], o[1]);
  *(ushort2*)(row + 2) = make_ushort2(o[2], o[3]);
  *(ushort2*)(row + 4) = make_ushort2(o[4], o[5]);
}

// ---------------- flash attention: 64 q-rows/block, 55 kv tiles of 64 ----------------
__global__ __launch_bounds__(256) void attn_kernel(const ushort* __restrict__ qb,
    const ushort* __restrict__ kb, const ushort* __restrict__ vT,
    ushort* __restrict__ ab) {
  __shared__ ushort Qs[64 * 128];
  __shared__ ushort Ks[64 * 128];
  __shared__ ushort Vs[128 * 64];
  __shared__ ushort Ps[4][16 * 72];
  const int qt = blockIdx.x;
  const int h  = blockIdx.y;
  const int t = threadIdx.x;
  const int lane = t & 63;
  const int w = t >> 6;

  {
    int rr = t >> 4, ck = t & 15;
#pragma unroll
    for (int i = 0; i < 4; ++i) {
      int row = rr + 16 * i;
      int cs = ck ^ (row & 7);
      gload16(qb + (long)(qt * 64 + row) * DIM + h * HD + cs * 8,
              (char*)Qs + row * 256 + ck * 16);
    }
  }
  __syncthreads();
  bf16x8 aq[4];
  {
    int row = 16 * w + (lane & 15);
#pragma unroll
    for (int ks = 0; ks < 4; ++ks) {
      int ck = (ks * 4 + (lane >> 4)) ^ (row & 7);
      aq[ks] = *(const bf16x8*)(Qs + row * 128 + ck * 8);
    }
  }

  f32x4 acc_o[8];
#pragma unroll
  for (int i = 0; i < 8; ++i) acc_o[i] = (f32x4)0.0f;
  float m_r[4] = {-1e30f, -1e30f, -1e30f, -1e30f};
  float l_r[4] = {0.f, 0.f, 0.f, 0.f};

  for (int it = 0; it < NKV; ++it) {
    const int kv0 = it * 64;
    __syncthreads();
    {
      int rr = t >> 4, ck = t & 15;
#pragma unroll
      for (int i = 0; i < 4; ++i) {
        int row = rr + 16 * i;
        int cs = ck ^ (row & 7);
        gload16(kb + (long)(kv0 + row) * DIM + h * HD + cs * 8,
                (char*)Ks + row * 256 + ck * 16);
      }
      int rv = t >> 3, cv = t & 7;
#pragma unroll
      for (int i = 0; i < 4; ++i) {
        int row = rv + 32 * i;
        int cs = cv ^ (row & 7);
        gload16(vT + (long)(h * HD + row) * LSEQ + kv0 + cs * 8,
                (char*)Vs + row * 128 + cv * 16);
      }
    }
    __syncthreads();

    f32x4 s[4];
#pragma unroll
    for (int nf = 0; nf < 4; ++nf) s[nf] = (f32x4)0.0f;
#pragma unroll
    for (int nf = 0; nf < 4; ++nf) {
      int row = 16 * nf + (lane & 15);
#pragma unroll
      for (int ks = 0; ks < 4; ++ks) {
        int ck = (ks * 4 + (lane >> 4)) ^ (row & 7);
        bf16x8 bk = *(const bf16x8*)(Ks + row * 128 + ck * 8);
        s[nf] = __builtin_amdgcn_mfma_f32_16x16x32_bf16(aq[ks], bk, s[nf], 0, 0, 0);
      }
    }
    // online softmax (q-row = (lane>>4)*4+j, kv = 16*nf + (lane&15))
#pragma unroll
    for (int j = 0; j < 4; ++j) {
      float sj0 = s[0][j] * SCALEF, sj1 = s[1][j] * SCALEF,
            sj2 = s[2][j] * SCALEF, sj3 = s[3][j] * SCALEF;
      float mx = fmaxf(fmaxf(sj0, sj1), fmaxf(sj2, sj3));
      mx = fmaxf(mx, __shfl_xor(mx, 1));
      mx = fmaxf(mx, __shfl_xor(mx, 2));
      mx = fmaxf(mx, __shfl_xor(mx, 4));
      mx = fmaxf(mx, __shfl_xor(mx, 8));
      float mnew = fmaxf(m_r[j], mx);
      float fj = __expf(m_r[j] - mnew);
      float p0 = __expf(sj0 - mnew), p1 = __expf(sj1 - mnew),
            p2 = __expf(sj2 - mnew), p3 = __expf(sj3 - mnew);
      float rs = p0 + p1 + p2 + p3;
      rs += __shfl_xor(rs, 1);
      rs += __shfl_xor(rs, 2);
      rs += __shfl_xor(rs, 4);
      rs += __shfl_xor(rs, 8);
      l_r[j] = l_r[j] * fj + rs;
      m_r[j] = mnew;
#pragma unroll
      for (int ni = 0; ni < 8; ++ni) acc_o[ni][j] *= fj;
      int prow = ((lane >> 4) * 4 + j) * 72 + (lane & 15);
      Ps[w][prow]      = f2bf(p0);
      Ps[w][prow + 16] = f2bf(p1);
      Ps[w][prow + 32] = f2bf(p2);
      Ps[w][prow + 48] = f2bf(p3);
    }
    // PV
#pragma unroll
    for (int ks = 0; ks < 2; ++ks) {
      bf16x8 ap = *(const bf16x8*)(&Ps[w][(lane & 15) * 72 + ks * 32 + (lane >> 4) * 8]);
#pragma unroll
      for (int ni = 0; ni < 8; ++ni) {
        int row = 16 * ni + (lane & 15);
        int ck = (ks * 4 + (lane >> 4)) ^ (row & 7);
        bf16x8 bv = *(const bf16x8*)(Vs + row * 64 + ck * 8);
        acc_o[ni] = __builtin_amdgcn_mfma_f32_16x16x32_bf16(ap, bv, acc_o[ni], 0, 0, 0);
      }
    }
  }

#pragma unroll
  for (int j = 0; j < 4; ++j) l_r[j] = 1.0f / l_r[j];
  const int qgb = qt * 64 + 16 * w + (lane >> 4) * 4;
#pragma unroll
  for (int ni = 0; ni < 8; ++ni) {
    int col = h * HD + 16 * ni + (lane & 15);
#pragma unroll
    for (int j = 0; j < 4; ++j)
      ab[(long)(qgb + j) * DIM + col] = f2bf(acc_o[ni][j] * l_r[j]);
  }
}

// ---------------------------------------------------------------------------
extern "C" void kernel_launch(void* const* d_in, const int* in_sizes, int n_in,
                              void* d_out, int out_size, void* d_ws, size_t ws_size,
                              hipStream_t stream) {
  const float* x     = (const float*)d_in[0];
  const float* freqs = (const float*)d_in[3];
  const float* Wq = (const float*)d_in[4];  const float* bq = (const float*)d_in[5];
  const float* Wk = (const float*)d_in[6];  const float* bk = (const float*)d_in[7];
  const float* Wv = (const float*)d_in[8];  const float* bv = (const float*)d_in[9];
  const float* Wo = (const float*)d_in[10]; const float* bo = (const float*)d_in[11];
  const float* gq = (const float*)d_in[12]; const float* gk = (const float*)d_in[13];

  char* ws = (char*)d_ws;
  size_t off = 0;
  auto alloc = [&](size_t bytes) -> char* {
    char* p = ws + off;
    off += (bytes + 255) & ~(size_t)255;
    return p;
  };
  ushort* xb  = (ushort*)alloc((size_t)MPAD * DIM * 2);   // 10.5 MB
  ushort* wqb = (ushort*)alloc((size_t)DIM * DIM * 2);    // 4.7 MB
  ushort* wkb = (ushort*)alloc((size_t)DIM * DIM * 2);
  ushort* wvb = (ushort*)alloc((size_t)DIM * DIM * 2);
  ushort* wob = (ushort*)alloc((size_t)DIM * DIM * 2);
  ushort* qbb = (ushort*)alloc((size_t)LSEQ * DIM * 2);   // 10.8 MB
  ushort* kbb = (ushort*)alloc((size_t)LSEQ * DIM * 2);
  ushort* vT  = (ushort*)alloc((size_t)DIM * LSEQ * 2);
  ushort* ab  = (ushort*)alloc((size_t)MPAD * DIM * 2);   // total ~73 MB

  cast_kernel<<<MPAD * DIM / 8 / 256, 256, 0, stream>>>(x, xb, (long)LSEQ * DIM);
  cast_kernel<<<DIM * DIM / 8 / 256, 256, 0, stream>>>(Wq, wqb, (long)DIM * DIM);
  cast_kernel<<<DIM * DIM / 8 / 256, 256, 0, stream>>>(Wk, wkb, (long)DIM * DIM);
  cast_kernel<<<DIM * DIM / 8 / 256, 256, 0, stream>>>(Wv, wvb, (long)DIM * DIM);
  cast_kernel<<<DIM * DIM / 8 / 256, 256, 0, stream>>>(Wo, wob, (long)DIM * DIM);

  dim3 gg(MPAD / 128, DIM / 128);
  gemm_bt<3><<<gg, 256, 0, stream>>>(xb, wqb, bq, nullptr, qbb);
  gemm_bt<3><<<gg, 256, 0, stream>>>(xb, wkb, bk, nullptr, kbb);
  gemm_bt<1><<<gg, 256, 0, stream>>>(xb, wvb, bv, nullptr, vT);

  postqk_kernel<<<dim3(LSEQ, 2), 256, 0, stream>>>(qbb, kbb, gq, gk, freqs);

  zero_tail_kernel<<<(MPAD - LSEQ) * DIM / 4 / 256, 256, 0, stream>>>(ab + (size_t)LSEQ * DIM);
  attn_kernel<<<dim3(NKV, HEADS), 256, 0, stream>>>(qbb, kbb, vT, ab);

  gemm_bt<2><<<gg, 256, 0, stream>>>(ab, wob, bo, (float*)d_out, nullptr);
}

// Round 3
// 436.516 us; speedup vs baseline: 1.1619x; 1.1619x over previous
//
#include <hip/hip_runtime.h>
#include <hip/hip_bf16.h>
#include <cstdint>

#define DIM   1536
#define HEADS 12
#define HD    128
#define LSEQ  3520
#define MPAD  3584
#define NKV   55
#define EPSF  1e-6f
// (1/sqrt(128)) * log2(e) — folded into q at postqk; attention softmax runs base-2
#define QSCL  0.12751729198891580f

typedef __attribute__((ext_vector_type(4))) float f32x4;
typedef __attribute__((ext_vector_type(8))) short bf16x8;

__device__ __forceinline__ void gload16(const void* g, void* l) {
  __builtin_amdgcn_global_load_lds(
      (const __attribute__((address_space(1))) void*)g,
      (__attribute__((address_space(3))) void*)l, 16, 0, 0);
}

__device__ __forceinline__ ushort f2bf(float f) {
  union { float f; unsigned u; } v; v.f = f;
  unsigned u = v.u;
  return (ushort)((u + 0x7FFFu + ((u >> 16) & 1u)) >> 16);
}

__device__ __forceinline__ float bf2f(ushort u) {
  union { unsigned u; float f; } v; v.u = ((unsigned)u) << 16;
  return v.f;
}

// ---- fused cast: x (zero-padded to MPAD rows) + 4 weights -> one contiguous bf16 region
__global__ __launch_bounds__(256) void cast_all(const float* __restrict__ x,
    const float* __restrict__ Wq, const float* __restrict__ Wk,
    const float* __restrict__ Wv, const float* __restrict__ Wo,
    ushort* __restrict__ dst) {
  long e = ((long)blockIdx.x * 256 + threadIdx.x) * 8;
  const float* src;
  long off;
  if (e < (long)MPAD * DIM) {
    if (e >= (long)LSEQ * DIM) {          // pad rows -> zeros
      *(bf16x8*)(dst + e) = (bf16x8)(short)0;
      return;
    }
    src = x; off = e;
  } else {
    long e2 = e - (long)MPAD * DIM;
    int wsel = (int)(e2 / ((long)DIM * DIM));
    off = e2 - (long)wsel * DIM * DIM;
    src = wsel == 0 ? Wq : (wsel == 1 ? Wk : (wsel == 2 ? Wv : Wo));
  }
  float4 a = *(const float4*)(src + off);
  float4 b = *(const float4*)(src + off + 4);
  bf16x8 o;
  o[0] = (short)f2bf(a.x); o[1] = (short)f2bf(a.y);
  o[2] = (short)f2bf(a.z); o[3] = (short)f2bf(a.w);
  o[4] = (short)f2bf(b.x); o[5] = (short)f2bf(b.y);
  o[6] = (short)f2bf(b.z); o[7] = (short)f2bf(b.w);
  *(bf16x8*)(dst + e) = o;
}

// ---- merged QKV GEMM: C[m][n] = sum_k A[m][k]*B3[n][k], n in [0,4608)
// which = n/1536: 0 -> qbb row-major bf16, 1 -> kbb row-major bf16, 2 -> vT transposed bf16
__global__ __launch_bounds__(256) void gemm_qkv(const ushort* __restrict__ A,
    const ushort* __restrict__ B3,
    const float* __restrict__ bq, const float* __restrict__ bk2, const float* __restrict__ bv2,
    ushort* __restrict__ qbb, ushort* __restrict__ kbb, ushort* __restrict__ vTt) {
  __shared__ ushort As[128 * 64];
  __shared__ ushort Bs[128 * 64];
  const int m0 = blockIdx.x * 128;
  const int n0g = blockIdx.y * 128;
  const int which = n0g / 1536;               // block-uniform
  const int n0l = n0g - which * 1536;
  const int t = threadIdx.x;
  const int lane = t & 63;
  const int w = t >> 6;
  const int wr = w >> 1, wc = w & 1;
  const int sr = t >> 3;
  const int sc = t & 7;

  f32x4 acc[4][4];
#pragma unroll
  for (int i = 0; i < 4; ++i)
#pragma unroll
    for (int j = 0; j < 4; ++j) acc[i][j] = (f32x4)0.0f;

  const int arow = 64 * wr + (lane & 15);
  const int brow = 64 * wc + (lane & 15);

  for (int k0 = 0; k0 < DIM; k0 += 64) {
    __syncthreads();
#pragma unroll
    for (int i = 0; i < 4; ++i) {
      int row = sr + 32 * i;
      int cs = sc ^ (row & 7);
      gload16(A + (long)(m0 + row) * DIM + k0 + cs * 8, (char*)As + row * 128 + sc * 16);
      gload16(B3 + (long)(n0g + row) * DIM + k0 + cs * 8, (char*)Bs + row * 128 + sc * 16);
    }
    __syncthreads();
    bf16x8 af[4][2], bfr[4][2];
#pragma unroll
    for (int mi = 0; mi < 4; ++mi) {
      int row = arow + 16 * mi;
#pragma unroll
      for (int ks = 0; ks < 2; ++ks) {
        int ck = (ks * 4 + (lane >> 4)) ^ (row & 7);
        af[mi][ks] = *(const bf16x8*)(As + row * 64 + ck * 8);
      }
    }
#pragma unroll
    for (int ni = 0; ni < 4; ++ni) {
      int row = brow + 16 * ni;
#pragma unroll
      for (int ks = 0; ks < 2; ++ks) {
        int ck = (ks * 4 + (lane >> 4)) ^ (row & 7);
        bfr[ni][ks] = *(const bf16x8*)(Bs + row * 64 + ck * 8);
      }
    }
#pragma unroll
    for (int mi = 0; mi < 4; ++mi)
#pragma unroll
      for (int ni = 0; ni < 4; ++ni)
#pragma unroll
        for (int ks = 0; ks < 2; ++ks)
          acc[mi][ni] = __builtin_amdgcn_mfma_f32_16x16x32_bf16(
              af[mi][ks], bfr[ni][ks], acc[mi][ni], 0, 0, 0);
  }

  const float* bias = which == 0 ? bq : (which == 1 ? bk2 : bv2);
#pragma unroll
  for (int mi = 0; mi < 4; ++mi) {
#pragma unroll
    for (int ni = 0; ni < 4; ++ni) {
      int gmb = m0 + 64 * wr + 16 * mi + (lane >> 4) * 4;
      int gnl = n0l + 64 * wc + 16 * ni + (lane & 15);
      float bvv = bias[gnl];
      if (which == 2) {
        if (gmb < LSEQ) {
          ushort4 o;
          o.x = f2bf(acc[mi][ni][0] + bvv);
          o.y = f2bf(acc[mi][ni][1] + bvv);
          o.z = f2bf(acc[mi][ni][2] + bvv);
          o.w = f2bf(acc[mi][ni][3] + bvv);
          *(ushort4*)(vTt + (long)gnl * LSEQ + gmb) = o;
        }
      } else {
        ushort* dst = which ? kbb : qbb;
        if (gmb < LSEQ) {
#pragma unroll
          for (int j = 0; j < 4; ++j)
            dst[(long)(gmb + j) * DIM + gnl] = f2bf(acc[mi][ni][j] + bvv);
        }
      }
    }
  }
}

// ---- output projection GEMM: fp32 out
__global__ __launch_bounds__(256) void gemm_out(const ushort* __restrict__ A,
    const ushort* __restrict__ B, const float* __restrict__ bias,
    float* __restrict__ Cf) {
  __shared__ ushort As[128 * 64];
  __shared__ ushort Bs[128 * 64];
  const int m0 = blockIdx.x * 128;
  const int n0 = blockIdx.y * 128;
  const int t = threadIdx.x;
  const int lane = t & 63;
  const int w = t >> 6;
  const int wr = w >> 1, wc = w & 1;
  const int sr = t >> 3;
  const int sc = t & 7;

  f32x4 acc[4][4];
#pragma unroll
  for (int i = 0; i < 4; ++i)
#pragma unroll
    for (int j = 0; j < 4; ++j) acc[i][j] = (f32x4)0.0f;

  const int arow = 64 * wr + (lane & 15);
  const int brow = 64 * wc + (lane & 15);

  for (int k0 = 0; k0 < DIM; k0 += 64) {
    __syncthreads();
#pragma unroll
    for (int i = 0; i < 4; ++i) {
      int row = sr + 32 * i;
      int cs = sc ^ (row & 7);
      gload16(A + (long)(m0 + row) * DIM + k0 + cs * 8, (char*)As + row * 128 + sc * 16);
      gload16(B + (long)(n0 + row) * DIM + k0 + cs * 8, (char*)Bs + row * 128 + sc * 16);
    }
    __syncthreads();
    bf16x8 af[4][2], bfr[4][2];
#pragma unroll
    for (int mi = 0; mi < 4; ++mi) {
      int row = arow + 16 * mi;
#pragma unroll
      for (int ks = 0; ks < 2; ++ks) {
        int ck = (ks * 4 + (lane >> 4)) ^ (row & 7);
        af[mi][ks] = *(const bf16x8*)(As + row * 64 + ck * 8);
      }
    }
#pragma unroll
    for (int ni = 0; ni < 4; ++ni) {
      int row = brow + 16 * ni;
#pragma unroll
      for (int ks = 0; ks < 2; ++ks) {
        int ck = (ks * 4 + (lane >> 4)) ^ (row & 7);
        bfr[ni][ks] = *(const bf16x8*)(Bs + row * 64 + ck * 8);
      }
    }
#pragma unroll
    for (int mi = 0; mi < 4; ++mi)
#pragma unroll
      for (int ni = 0; ni < 4; ++ni)
#pragma unroll
        for (int ks = 0; ks < 2; ++ks)
          acc[mi][ni] = __builtin_amdgcn_mfma_f32_16x16x32_bf16(
              af[mi][ks], bfr[ni][ks], acc[mi][ni], 0, 0, 0);
  }

#pragma unroll
  for (int mi = 0; mi < 4; ++mi) {
#pragma unroll
    for (int ni = 0; ni < 4; ++ni) {
      int gmb = m0 + 64 * wr + 16 * mi + (lane >> 4) * 4;
      int gn  = n0 + 64 * wc + 16 * ni + (lane & 15);
      float bvv = bias[gn];
      if (gmb < LSEQ) {
#pragma unroll
        for (int j = 0; j < 4; ++j)
          Cf[(long)(gmb + j) * DIM + gn] = acc[mi][ni][j] + bvv;
      }
    }
  }
}

// ---- in-place bf16: RMSNorm -> RoPE; q additionally scaled by QSCL ----
__global__ __launch_bounds__(256) void postqk_kernel(ushort* __restrict__ qb,
    ushort* __restrict__ kb, const float* __restrict__ gq_,
    const float* __restrict__ gk_, const float* __restrict__ freqs) {
  const int l = blockIdx.x;
  const int t = threadIdx.x;
  ushort* buf      = blockIdx.y ? kb : qb;
  const float* g   = blockIdx.y ? gk_ : gq_;
  const float post = blockIdx.y ? 1.0f : QSCL;
  ushort* row = buf + (long)l * DIM + t * 6;
  float v[6];
  {
    ushort2 p0 = *(const ushort2*)(row);
    ushort2 p1 = *(const ushort2*)(row + 2);
    ushort2 p2 = *(const ushort2*)(row + 4);
    v[0] = bf2f(p0.x); v[1] = bf2f(p0.y); v[2] = bf2f(p1.x);
    v[3] = bf2f(p1.y); v[4] = bf2f(p2.x); v[5] = bf2f(p2.y);
  }
  float ss = v[0]*v[0] + v[1]*v[1] + v[2]*v[2] + v[3]*v[3] + v[4]*v[4] + v[5]*v[5];
#pragma unroll
  for (int off = 1; off < 64; off <<= 1) ss += __shfl_xor(ss, off);
  __shared__ float red[4];
  if ((t & 63) == 0) red[t >> 6] = ss;
  __syncthreads();
  float scale = rsqrtf((red[0] + red[1] + red[2] + red[3]) * (1.0f / DIM) + EPSF) * post;
  const int fi = l / (22 * 40);
  const int hi = (l / 40) % 22;
  const int wi = l % 40;
  ushort o[6];
#pragma unroll
  for (int ii = 0; ii < 3; ++ii) {
    int pg = t * 3 + ii;
    int c = pg & 63;
    int rsel = (c < 22) ? fi : ((c < 43) ? hi : wi);
    float ang = freqs[rsel * 64 + c];
    float sn, cs;
    __sincosf(ang, &sn, &cs);
    float x0 = v[2*ii]   * scale * g[t*6 + 2*ii];
    float x1 = v[2*ii+1] * scale * g[t*6 + 2*ii+1];
    o[2*ii]   = f2bf(x0 * cs - x1 * sn);
    o[2*ii+1] = f2bf(x0 * sn + x1 * cs);
  }
  *(ushort2*)(row)     = make_ushort2(o[0], o[1]);
  *(ushort2*)(row + 2) = make_ushort2(o[2], o[3]);
  *(ushort2*)(row + 4) = make_ushort2(o[4], o[5]);
}

// ---- flash attention, swapped operands (S^T / O^T), double-buffered K/V ----
__global__ __launch_bounds__(256) void attn_kernel(const ushort* __restrict__ qb,
    const ushort* __restrict__ kb, const ushort* __restrict__ vT,
    ushort* __restrict__ ab) {
  __shared__ ushort KV[2][2][8192];   // [buf][0=K(64x128) 1=V(128x64)]
  __shared__ ushort Ps[4][16 * 72];
  const int qt = blockIdx.x;
  const int h  = blockIdx.y;
  const int t = threadIdx.x;
  const int lane = t & 63;
  const int w = t >> 6;
  const int q16 = lane & 15;
  const int hi = lane >> 4;

  auto stageKV = [&](int buf, int kv0) {
    int rr = t >> 4, ck = t & 15;
#pragma unroll
    for (int i = 0; i < 4; ++i) {
      int row = rr + 16 * i;
      int cs = ck ^ (row & 7);
      gload16(kb + (long)(kv0 + row) * DIM + h * HD + cs * 8,
              (char*)&KV[buf][0][0] + row * 256 + ck * 16);
    }
    int rv = t >> 3, cv = t & 7;
#pragma unroll
    for (int i = 0; i < 4; ++i) {
      int row = rv + 32 * i;
      int cs = cv ^ (row & 7);
      gload16(vT + (long)(h * HD + row) * LSEQ + kv0 + cs * 8,
              (char*)&KV[buf][1][0] + row * 128 + cv * 16);
    }
  };

  // stage Q (scaled by QSCL at postqk) into KV[1][0]
  {
    int rr = t >> 4, ck = t & 15;
#pragma unroll
    for (int i = 0; i < 4; ++i) {
      int row = rr + 16 * i;
      int cs = ck ^ (row & 7);
      gload16(qb + (long)(qt * 64 + row) * DIM + h * HD + cs * 8,
              (char*)&KV[1][0][0] + row * 256 + ck * 16);
    }
  }
  stageKV(0, 0);                                  // 8 loads (tile 0)
  asm volatile("s_waitcnt vmcnt(8)" ::: "memory");  // Q's 4 done
  __builtin_amdgcn_s_barrier();

  bf16x8 aq[4];
  {
    int row = 16 * w + q16;
#pragma unroll
    for (int ks = 0; ks < 4; ++ks) {
      int ck = (ks * 4 + hi) ^ (row & 7);
      aq[ks] = *(const bf16x8*)((const char*)&KV[1][0][0] + row * 256 + ck * 16);
    }
  }
  asm volatile("s_waitcnt lgkmcnt(0)" ::: "memory");  // Q reads done before buf1 overwritten
  __builtin_amdgcn_s_barrier();

  f32x4 acc_o[8];
#pragma unroll
  for (int i = 0; i < 8; ++i) acc_o[i] = (f32x4)0.0f;
  float m_r = -1e30f, l_r = 0.0f;

  auto compute = [&](int buf) {
    const ushort* Ks = &KV[buf][0][0];
    const ushort* Vs = &KV[buf][1][0];
    // S^T = mfma(K, Q): per lane: q = 16w+q16, kv = 16*nf + hi*4 + j (base-2 logits)
    f32x4 s[4];
#pragma unroll
    for (int nf = 0; nf < 4; ++nf) {
      s[nf] = (f32x4)0.0f;
      int row = 16 * nf + q16;
#pragma unroll
      for (int ks = 0; ks < 4; ++ks) {
        int ck = (ks * 4 + hi) ^ (row & 7);
        bf16x8 bk = *(const bf16x8*)(Ks + row * 128 + ck * 8);
        s[nf] = __builtin_amdgcn_mfma_f32_16x16x32_bf16(bk, aq[ks], s[nf], 0, 0, 0);
      }
    }
    // lane-local softmax over 16 values, reduce across hi-groups (xor 16, 32)
    float mx = s[0][0];
#pragma unroll
    for (int nf = 0; nf < 4; ++nf)
#pragma unroll
      for (int j = 0; j < 4; ++j) mx = fmaxf(mx, s[nf][j]);
    mx = fmaxf(mx, __shfl_xor(mx, 16));
    mx = fmaxf(mx, __shfl_xor(mx, 32));
    float mnew = fmaxf(m_r, mx);
    float fj = exp2f(m_r - mnew);
    float p[16], rs = 0.0f;
#pragma unroll
    for (int nf = 0; nf < 4; ++nf)
#pragma unroll
      for (int j = 0; j < 4; ++j) {
        float pv = exp2f(s[nf][j] - mnew);
        p[nf * 4 + j] = pv;
        rs += pv;
      }
    rs += __shfl_xor(rs, 16);
    rs += __shfl_xor(rs, 32);
    l_r = l_r * fj + rs;
    m_r = mnew;
#pragma unroll
    for (int ni = 0; ni < 8; ++ni) acc_o[ni] *= fj;
    // P^T -> LDS: row q16, kv = 16*nf + hi*4 + j  (packed b64 writes)
#pragma unroll
    for (int nf = 0; nf < 4; ++nf) {
      ushort4 o;
      o.x = f2bf(p[nf * 4 + 0]);
      o.y = f2bf(p[nf * 4 + 1]);
      o.z = f2bf(p[nf * 4 + 2]);
      o.w = f2bf(p[nf * 4 + 3]);
      *(ushort4*)(&Ps[w][q16 * 72 + nf * 16 + hi * 4]) = o;
    }
    // O^T += mfma(V^T, P^T): rows d, cols q
#pragma unroll
    for (int ks = 0; ks < 2; ++ks) {
      bf16x8 ap = *(const bf16x8*)(&Ps[w][q16 * 72 + ks * 32 + hi * 8]);
#pragma unroll
      for (int ni = 0; ni < 8; ++ni) {
        int row = 16 * ni + q16;
        int ck = (ks * 4 + hi) ^ (row & 7);
        bf16x8 bv = *(const bf16x8*)(Vs + row * 64 + ck * 8);
        acc_o[ni] = __builtin_amdgcn_mfma_f32_16x16x32_bf16(bv, ap, acc_o[ni], 0, 0, 0);
      }
    }
  };

  for (int tt = 0; tt < NKV - 1; ++tt) {
    stageKV((tt + 1) & 1, (tt + 1) * 64);            // issue next tile (8 loads)
    asm volatile("s_waitcnt vmcnt(8)" ::: "memory");  // current tile's loads done
    __builtin_amdgcn_s_barrier();
    compute(tt & 1);
    __builtin_amdgcn_s_barrier();                     // all reads of cur buf done
  }
  asm volatile("s_waitcnt vmcnt(0)" ::: "memory");
  __builtin_amdgcn_s_barrier();
  compute((NKV - 1) & 1);

  float inv_l = 1.0f / l_r;
  const int qg = qt * 64 + 16 * w + q16;
#pragma unroll
  for (int ni = 0; ni < 8; ++ni) {
    ushort4 o;
    o.x = f2bf(acc_o[ni][0] * inv_l);
    o.y = f2bf(acc_o[ni][1] * inv_l);
    o.z = f2bf(acc_o[ni][2] * inv_l);
    o.w = f2bf(acc_o[ni][3] * inv_l);
    *(ushort4*)(ab + (long)qg * DIM + h * HD + 16 * ni + hi * 4) = o;
  }
}

// ---------------------------------------------------------------------------
extern "C" void kernel_launch(void* const* d_in, const int* in_sizes, int n_in,
                              void* d_out, int out_size, void* d_ws, size_t ws_size,
                              hipStream_t stream) {
  const float* x     = (const float*)d_in[0];
  const float* freqs = (const float*)d_in[3];
  const float* Wq = (const float*)d_in[4];  const float* bq = (const float*)d_in[5];
  const float* Wk = (const float*)d_in[6];  const float* bk = (const float*)d_in[7];
  const float* Wv = (const float*)d_in[8];  const float* bv = (const float*)d_in[9];
  const float* Wo = (const float*)d_in[10]; const float* bo = (const float*)d_in[11];
  const float* gq = (const float*)d_in[12]; const float* gk = (const float*)d_in[13];

  char* ws = (char*)d_ws;
  size_t off = 0;
  auto alloc = [&](size_t bytes) -> char* {
    char* p = ws + off;
    off += (bytes + 255) & ~(size_t)255;
    return p;
  };
  // xb and the 4 weights must be contiguous (cast_all writes one region)
  ushort* xb   = (ushort*)alloc((size_t)MPAD * DIM * 2 + 4 * (size_t)DIM * DIM * 2);
  ushort* wall = xb + (size_t)MPAD * DIM;           // wq|wk|wv|wo
  ushort* wob  = wall + 3 * (size_t)DIM * DIM;
  ushort* qbb = (ushort*)alloc((size_t)LSEQ * DIM * 2);
  ushort* kbb = (ushort*)alloc((size_t)LSEQ * DIM * 2);
  ushort* vT  = (ushort*)alloc((size_t)DIM * LSEQ * 2);
  ushort* ab  = (ushort*)alloc((size_t)MPAD * DIM * 2);

  const long tot8 = ((long)MPAD * DIM + 4L * DIM * DIM) / 8;
  cast_all<<<(int)(tot8 / 256), 256, 0, stream>>>(x, Wq, Wk, Wv, Wo, xb);

  gemm_qkv<<<dim3(MPAD / 128, 36), 256, 0, stream>>>(xb, wall, bq, bk, bv, qbb, kbb, vT);

  postqk_kernel<<<dim3(LSEQ, 2), 256, 0, stream>>>(qbb, kbb, gq, gk, freqs);

  attn_kernel<<<dim3(NKV, HEADS), 256, 0, stream>>>(qbb, kbb, vT, ab);

  gemm_out<<<dim3(MPAD / 128, DIM / 128), 256, 0, stream>>>(ab, wob, bo, (float*)d_out);
}

// Round 4
// 403.358 us; speedup vs baseline: 1.2574x; 1.0822x over previous
//
#include <hip/hip_runtime.h>
#include <hip/hip_bf16.h>
#include <cstdint>

#define DIM   1536
#define HEADS 12
#define HD    128
#define LSEQ  3520
#define MPAD  3584
#define NKV   55
#define EPSF  1e-6f
// (1/sqrt(128)) * log2(e) — folded into q at postqk; attention softmax runs base-2
#define QSCL  0.12751729198891580f

typedef __attribute__((ext_vector_type(4))) float f32x4;
typedef __attribute__((ext_vector_type(8))) short bf16x8;

__device__ __forceinline__ void gload16(const void* g, void* l) {
  __builtin_amdgcn_global_load_lds(
      (const __attribute__((address_space(1))) void*)g,
      (__attribute__((address_space(3))) void*)l, 16, 0, 0);
}

__device__ __forceinline__ ushort f2bf(float f) {
  union { float f; unsigned u; } v; v.f = f;
  unsigned u = v.u;
  return (ushort)((u + 0x7FFFu + ((u >> 16) & 1u)) >> 16);
}

__device__ __forceinline__ float bf2f(ushort u) {
  union { unsigned u; float f; } v; v.u = ((unsigned)u) << 16;
  return v.f;
}

#if __has_builtin(__builtin_amdgcn_exp2f)
__device__ __forceinline__ float ex2(float x) { return __builtin_amdgcn_exp2f(x); }
#else
__device__ __forceinline__ float ex2(float x) { return exp2f(x); }
#endif

__device__ __forceinline__ unsigned cvtpk(float a, float b) {
  unsigned r;
  asm("v_cvt_pk_bf16_f32 %0, %1, %2" : "=v"(r) : "v"(a), "v"(b));
  return r;
}

// ---- fused cast: x (zero-padded to MPAD rows) + 4 weights -> one contiguous bf16 region
__global__ __launch_bounds__(256) void cast_all(const float* __restrict__ x,
    const float* __restrict__ Wq, const float* __restrict__ Wk,
    const float* __restrict__ Wv, const float* __restrict__ Wo,
    ushort* __restrict__ dst) {
  long e = ((long)blockIdx.x * 256 + threadIdx.x) * 8;
  const float* src;
  long off;
  if (e < (long)MPAD * DIM) {
    if (e >= (long)LSEQ * DIM) {          // pad rows -> zeros
      *(bf16x8*)(dst + e) = (bf16x8)(short)0;
      return;
    }
    src = x; off = e;
  } else {
    long e2 = e - (long)MPAD * DIM;
    int wsel = (int)(e2 / ((long)DIM * DIM));
    off = e2 - (long)wsel * DIM * DIM;
    src = wsel == 0 ? Wq : (wsel == 1 ? Wk : (wsel == 2 ? Wv : Wo));
  }
  float4 a = *(const float4*)(src + off);
  float4 b = *(const float4*)(src + off + 4);
  bf16x8 o;
  o[0] = (short)f2bf(a.x); o[1] = (short)f2bf(a.y);
  o[2] = (short)f2bf(a.z); o[3] = (short)f2bf(a.w);
  o[4] = (short)f2bf(b.x); o[5] = (short)f2bf(b.y);
  o[6] = (short)f2bf(b.z); o[7] = (short)f2bf(b.w);
  *(bf16x8*)(dst + e) = o;
}

// ---- merged QKV GEMM: C[m][n] = sum_k A[m][k]*B3[n][k], n in [0,4608)
// which = n/1536: 0 -> qbb row-major bf16, 1 -> kbb row-major bf16, 2 -> vT transposed bf16
__global__ __launch_bounds__(256) void gemm_qkv(const ushort* __restrict__ A,
    const ushort* __restrict__ B3,
    const float* __restrict__ bq, const float* __restrict__ bk2, const float* __restrict__ bv2,
    ushort* __restrict__ qbb, ushort* __restrict__ kbb, ushort* __restrict__ vTt) {
  __shared__ ushort As[128 * 64];
  __shared__ ushort Bs[128 * 64];
  const int m0 = blockIdx.x * 128;
  const int n0g = blockIdx.y * 128;
  const int which = n0g / 1536;               // block-uniform
  const int n0l = n0g - which * 1536;
  const int t = threadIdx.x;
  const int lane = t & 63;
  const int w = t >> 6;
  const int wr = w >> 1, wc = w & 1;
  const int sr = t >> 3;
  const int sc = t & 7;

  f32x4 acc[4][4];
#pragma unroll
  for (int i = 0; i < 4; ++i)
#pragma unroll
    for (int j = 0; j < 4; ++j) acc[i][j] = (f32x4)0.0f;

  const int arow = 64 * wr + (lane & 15);
  const int brow = 64 * wc + (lane & 15);

  for (int k0 = 0; k0 < DIM; k0 += 64) {
    __syncthreads();
#pragma unroll
    for (int i = 0; i < 4; ++i) {
      int row = sr + 32 * i;
      int cs = sc ^ (row & 7);
      gload16(A + (long)(m0 + row) * DIM + k0 + cs * 8, (char*)As + row * 128 + sc * 16);
      gload16(B3 + (long)(n0g + row) * DIM + k0 + cs * 8, (char*)Bs + row * 128 + sc * 16);
    }
    __syncthreads();
    bf16x8 af[4][2], bfr[4][2];
#pragma unroll
    for (int mi = 0; mi < 4; ++mi) {
      int row = arow + 16 * mi;
#pragma unroll
      for (int ks = 0; ks < 2; ++ks) {
        int ck = (ks * 4 + (lane >> 4)) ^ (row & 7);
        af[mi][ks] = *(const bf16x8*)(As + row * 64 + ck * 8);
      }
    }
#pragma unroll
    for (int ni = 0; ni < 4; ++ni) {
      int row = brow + 16 * ni;
#pragma unroll
      for (int ks = 0; ks < 2; ++ks) {
        int ck = (ks * 4 + (lane >> 4)) ^ (row & 7);
        bfr[ni][ks] = *(const bf16x8*)(Bs + row * 64 + ck * 8);
      }
    }
#pragma unroll
    for (int mi = 0; mi < 4; ++mi)
#pragma unroll
      for (int ni = 0; ni < 4; ++ni)
#pragma unroll
        for (int ks = 0; ks < 2; ++ks)
          acc[mi][ni] = __builtin_amdgcn_mfma_f32_16x16x32_bf16(
              af[mi][ks], bfr[ni][ks], acc[mi][ni], 0, 0, 0);
  }

  const float* bias = which == 0 ? bq : (which == 1 ? bk2 : bv2);
#pragma unroll
  for (int mi = 0; mi < 4; ++mi) {
#pragma unroll
    for (int ni = 0; ni < 4; ++ni) {
      int gmb = m0 + 64 * wr + 16 * mi + (lane >> 4) * 4;
      int gnl = n0l + 64 * wc + 16 * ni + (lane & 15);
      float bvv = bias[gnl];
      if (which == 2) {
        if (gmb < LSEQ) {
          ushort4 o;
          o.x = f2bf(acc[mi][ni][0] + bvv);
          o.y = f2bf(acc[mi][ni][1] + bvv);
          o.z = f2bf(acc[mi][ni][2] + bvv);
          o.w = f2bf(acc[mi][ni][3] + bvv);
          *(ushort4*)(vTt + (long)gnl * LSEQ + gmb) = o;
        }
      } else {
        ushort* dst = which ? kbb : qbb;
        if (gmb < LSEQ) {
#pragma unroll
          for (int j = 0; j < 4; ++j)
            dst[(long)(gmb + j) * DIM + gnl] = f2bf(acc[mi][ni][j] + bvv);
        }
      }
    }
  }
}

// ---- output projection GEMM: fp32 out
__global__ __launch_bounds__(256) void gemm_out(const ushort* __restrict__ A,
    const ushort* __restrict__ B, const float* __restrict__ bias,
    float* __restrict__ Cf) {
  __shared__ ushort As[128 * 64];
  __shared__ ushort Bs[128 * 64];
  const int m0 = blockIdx.x * 128;
  const int n0 = blockIdx.y * 128;
  const int t = threadIdx.x;
  const int lane = t & 63;
  const int w = t >> 6;
  const int wr = w >> 1, wc = w & 1;
  const int sr = t >> 3;
  const int sc = t & 7;

  f32x4 acc[4][4];
#pragma unroll
  for (int i = 0; i < 4; ++i)
#pragma unroll
    for (int j = 0; j < 4; ++j) acc[i][j] = (f32x4)0.0f;

  const int arow = 64 * wr + (lane & 15);
  const int brow = 64 * wc + (lane & 15);

  for (int k0 = 0; k0 < DIM; k0 += 64) {
    __syncthreads();
#pragma unroll
    for (int i = 0; i < 4; ++i) {
      int row = sr + 32 * i;
      int cs = sc ^ (row & 7);
      gload16(A + (long)(m0 + row) * DIM + k0 + cs * 8, (char*)As + row * 128 + sc * 16);
      gload16(B + (long)(n0 + row) * DIM + k0 + cs * 8, (char*)Bs + row * 128 + sc * 16);
    }
    __syncthreads();
    bf16x8 af[4][2], bfr[4][2];
#pragma unroll
    for (int mi = 0; mi < 4; ++mi) {
      int row = arow + 16 * mi;
#pragma unroll
      for (int ks = 0; ks < 2; ++ks) {
        int ck = (ks * 4 + (lane >> 4)) ^ (row & 7);
        af[mi][ks] = *(const bf16x8*)(As + row * 64 + ck * 8);
      }
    }
#pragma unroll
    for (int ni = 0; ni < 4; ++ni) {
      int row = brow + 16 * ni;
#pragma unroll
      for (int ks = 0; ks < 2; ++ks) {
        int ck = (ks * 4 + (lane >> 4)) ^ (row & 7);
        bfr[ni][ks] = *(const bf16x8*)(Bs + row * 64 + ck * 8);
      }
    }
#pragma unroll
    for (int mi = 0; mi < 4; ++mi)
#pragma unroll
      for (int ni = 0; ni < 4; ++ni)
#pragma unroll
        for (int ks = 0; ks < 2; ++ks)
          acc[mi][ni] = __builtin_amdgcn_mfma_f32_16x16x32_bf16(
              af[mi][ks], bfr[ni][ks], acc[mi][ni], 0, 0, 0);
  }

#pragma unroll
  for (int mi = 0; mi < 4; ++mi) {
#pragma unroll
    for (int ni = 0; ni < 4; ++ni) {
      int gmb = m0 + 64 * wr + 16 * mi + (lane >> 4) * 4;
      int gn  = n0 + 64 * wc + 16 * ni + (lane & 15);
      float bvv = bias[gn];
      if (gmb < LSEQ) {
#pragma unroll
        for (int j = 0; j < 4; ++j)
          Cf[(long)(gmb + j) * DIM + gn] = acc[mi][ni][j] + bvv;
      }
    }
  }
}

// ---- in-place bf16: RMSNorm -> RoPE; q additionally scaled by QSCL ----
__global__ __launch_bounds__(256) void postqk_kernel(ushort* __restrict__ qb,
    ushort* __restrict__ kb, const float* __restrict__ gq_,
    const float* __restrict__ gk_, const float* __restrict__ freqs) {
  const int l = blockIdx.x;
  const int t = threadIdx.x;
  ushort* buf      = blockIdx.y ? kb : qb;
  const float* g   = blockIdx.y ? gk_ : gq_;
  const float post = blockIdx.y ? 1.0f : QSCL;
  ushort* row = buf + (long)l * DIM + t * 6;
  float v[6];
  {
    ushort2 p0 = *(const ushort2*)(row);
    ushort2 p1 = *(const ushort2*)(row + 2);
    ushort2 p2 = *(const ushort2*)(row + 4);
    v[0] = bf2f(p0.x); v[1] = bf2f(p0.y); v[2] = bf2f(p1.x);
    v[3] = bf2f(p1.y); v[4] = bf2f(p2.x); v[5] = bf2f(p2.y);
  }
  float ss = v[0]*v[0] + v[1]*v[1] + v[2]*v[2] + v[3]*v[3] + v[4]*v[4] + v[5]*v[5];
#pragma unroll
  for (int off = 1; off < 64; off <<= 1) ss += __shfl_xor(ss, off);
  __shared__ float red[4];
  if ((t & 63) == 0) red[t >> 6] = ss;
  __syncthreads();
  float scale = rsqrtf((red[0] + red[1] + red[2] + red[3]) * (1.0f / DIM) + EPSF) * post;
  const int fi = l / (22 * 40);
  const int hi = (l / 40) % 22;
  const int wi = l % 40;
  ushort o[6];
#pragma unroll
  for (int ii = 0; ii < 3; ++ii) {
    int pg = t * 3 + ii;
    int c = pg & 63;
    int rsel = (c < 22) ? fi : ((c < 43) ? hi : wi);
    float ang = freqs[rsel * 64 + c];
    float sn, cs;
    __sincosf(ang, &sn, &cs);
    float x0 = v[2*ii]   * scale * g[t*6 + 2*ii];
    float x1 = v[2*ii+1] * scale * g[t*6 + 2*ii+1];
    o[2*ii]   = f2bf(x0 * cs - x1 * sn);
    o[2*ii+1] = f2bf(x0 * sn + x1 * cs);
  }
  *(ushort2*)(row)     = make_ushort2(o[0], o[1]);
  *(ushort2*)(row + 2) = make_ushort2(o[2], o[3]);
  *(ushort2*)(row + 4) = make_ushort2(o[4], o[5]);
}

// ---- flash attention: 2 q-halves x 2 kv-streams per block, independent online
// softmax per stream, flash-combine at end. Swapped operands (S^T/O^T) throughout.
__global__ __launch_bounds__(256) void attn_kernel(const ushort* __restrict__ qb,
    const ushort* __restrict__ kb, const ushort* __restrict__ vT,
    ushort* __restrict__ ab) {
  __shared__ ushort KV[2][2][8192];   // [buf][0=K(64x128) 1=V(128x64)]
  __shared__ ushort Ps[4][32 * 40];   // per-wave P^T [32 q][32 kv], pad 40
  __shared__ float2 Msh[4][2][16];    // per-wave (m,l) per qf per q16
  const int qt = blockIdx.x;
  const int h  = blockIdx.y;
  const int t = threadIdx.x;
  const int lane = t & 63;
  const int w = t >> 6;
  const int a = w >> 1;      // q-half (32 rows)
  const int b = w & 1;       // kv-stream (32 of each 64-tile)
  const int q16 = lane & 15;
  const int hi = lane >> 4;

  auto stageKV = [&](int buf, int kv0) {
    int rr = t >> 4, ck = t & 15;
#pragma unroll
    for (int i = 0; i < 4; ++i) {
      int row = rr + 16 * i;
      int cs = ck ^ (row & 7);
      gload16(kb + (long)(kv0 + row) * DIM + h * HD + cs * 8,
              (char*)&KV[buf][0][0] + row * 256 + ck * 16);
    }
    int rv = t >> 3, cv = t & 7;
#pragma unroll
    for (int i = 0; i < 4; ++i) {
      int row = rv + 32 * i;
      int cs = cv ^ (row & 7);
      gload16(vT + (long)(h * HD + row) * LSEQ + kv0 + cs * 8,
              (char*)&KV[buf][1][0] + row * 128 + cv * 16);
    }
  };

  // stage Q (scaled by QSCL*log2e at postqk) into KV[1][0]
  {
    int rr = t >> 4, ck = t & 15;
#pragma unroll
    for (int i = 0; i < 4; ++i) {
      int row = rr + 16 * i;
      int cs = ck ^ (row & 7);
      gload16(qb + (long)(qt * 64 + row) * DIM + h * HD + cs * 8,
              (char*)&KV[1][0][0] + row * 256 + ck * 16);
    }
  }
  stageKV(0, 0);
  asm volatile("s_waitcnt vmcnt(8)" ::: "memory");   // Q's 4 done
  __builtin_amdgcn_s_barrier();

  bf16x8 aq[2][4];   // Q fragments: q = a*32 + qf*16 + q16, k = ks*32 + hi*8..
#pragma unroll
  for (int qf = 0; qf < 2; ++qf) {
    int row = a * 32 + qf * 16 + q16;
#pragma unroll
    for (int ks = 0; ks < 4; ++ks) {
      int ck = (ks * 4 + hi) ^ (row & 7);
      aq[qf][ks] = *(const bf16x8*)((const char*)&KV[1][0][0] + row * 256 + ck * 16);
    }
  }
  asm volatile("s_waitcnt lgkmcnt(0)" ::: "memory");
  __builtin_amdgcn_s_barrier();

  f32x4 acc[8][2];           // O^T partial: d = 16ni+4hi+j, q = a*32+qf*16+q16
#pragma unroll
  for (int i = 0; i < 8; ++i) { acc[i][0] = (f32x4)0.0f; acc[i][1] = (f32x4)0.0f; }
  float m_r[2] = {-1e30f, -1e30f};
  float l_r[2] = {0.f, 0.f};
  ushort* Psw = &Ps[w][0];

  auto compute = [&](int buf) {
    const ushort* Ks = &KV[buf][0][0];
    const ushort* Vs = &KV[buf][1][0];
    // S^T = mfma(K-slice, Q): kv = b*32 + kf*16 + 4hi + j, q = a*32 + qf*16 + q16
    f32x4 s[2][2];
    s[0][0] = (f32x4)0.0f; s[0][1] = (f32x4)0.0f;
    s[1][0] = (f32x4)0.0f; s[1][1] = (f32x4)0.0f;
    __builtin_amdgcn_s_setprio(1);
#pragma unroll
    for (int kf = 0; kf < 2; ++kf) {
      int krow = b * 32 + kf * 16 + q16;
#pragma unroll
      for (int ks = 0; ks < 4; ++ks) {
        int ck = (ks * 4 + hi) ^ (krow & 7);
        bf16x8 kk = *(const bf16x8*)(Ks + krow * 128 + ck * 8);
        s[kf][0] = __builtin_amdgcn_mfma_f32_16x16x32_bf16(kk, aq[0][ks], s[kf][0], 0, 0, 0);
        s[kf][1] = __builtin_amdgcn_mfma_f32_16x16x32_bf16(kk, aq[1][ks], s[kf][1], 0, 0, 0);
      }
    }
    __builtin_amdgcn_s_setprio(0);
    // per-stream online softmax (base-2), defer-max
    float mx[2];
#pragma unroll
    for (int qf = 0; qf < 2; ++qf) {
      float m01 = fmaxf(fmaxf(s[0][qf][0], s[0][qf][1]), s[0][qf][2]);
      m01 = fmaxf(fmaxf(m01, s[0][qf][3]), s[1][qf][0]);
      m01 = fmaxf(fmaxf(m01, s[1][qf][1]), s[1][qf][2]);
      m01 = fmaxf(m01, s[1][qf][3]);
      m01 = fmaxf(m01, __shfl_xor(m01, 16));
      mx[qf] = fmaxf(m01, __shfl_xor(m01, 32));
    }
    bool noskip = !__all((mx[0] <= m_r[0] + 8.0f) & (mx[1] <= m_r[1] + 8.0f));
    if (noskip) {
#pragma unroll
      for (int qf = 0; qf < 2; ++qf) {
        float mnew = fmaxf(m_r[qf], mx[qf]);
        float fj = ex2(m_r[qf] - mnew);
        l_r[qf] *= fj;
        m_r[qf] = mnew;
#pragma unroll
        for (int ni = 0; ni < 8; ++ni) acc[ni][qf] *= fj;
      }
    }
#pragma unroll
    for (int qf = 0; qf < 2; ++qf) {
      float rs = 0.0f;
#pragma unroll
      for (int kf = 0; kf < 2; ++kf) {
        float p0 = ex2(s[kf][qf][0] - m_r[qf]);
        float p1 = ex2(s[kf][qf][1] - m_r[qf]);
        float p2 = ex2(s[kf][qf][2] - m_r[qf]);
        float p3 = ex2(s[kf][qf][3] - m_r[qf]);
        rs += (p0 + p1) + (p2 + p3);
        uint2 u;
        u.x = cvtpk(p0, p1);
        u.y = cvtpk(p2, p3);
        *(uint2*)(&Psw[(qf * 16 + q16) * 40 + kf * 16 + hi * 4]) = u;
      }
      rs += __shfl_xor(rs, 16);
      rs += __shfl_xor(rs, 32);
      l_r[qf] += rs;
    }
    // O^T += mfma(V^T-slice, P^T): k = kv_local 32
    bf16x8 pf[2];
    pf[0] = *(const bf16x8*)(&Psw[(0 * 16 + q16) * 40 + hi * 8]);
    pf[1] = *(const bf16x8*)(&Psw[(1 * 16 + q16) * 40 + hi * 8]);
    __builtin_amdgcn_s_setprio(1);
#pragma unroll
    for (int ni = 0; ni < 8; ++ni) {
      int vrow = 16 * ni + q16;
      int ck = (4 * b + hi) ^ (vrow & 7);
      bf16x8 vv = *(const bf16x8*)(Vs + vrow * 64 + ck * 8);
      acc[ni][0] = __builtin_amdgcn_mfma_f32_16x16x32_bf16(vv, pf[0], acc[ni][0], 0, 0, 0);
      acc[ni][1] = __builtin_amdgcn_mfma_f32_16x16x32_bf16(vv, pf[1], acc[ni][1], 0, 0, 0);
    }
    __builtin_amdgcn_s_setprio(0);
  };

  for (int tt = 0; tt < NKV - 1; ++tt) {
    stageKV((tt + 1) & 1, (tt + 1) * 64);
    asm volatile("s_waitcnt vmcnt(8)" ::: "memory");
    __builtin_amdgcn_s_barrier();
    compute(tt & 1);
    __builtin_amdgcn_s_barrier();
  }
  asm volatile("s_waitcnt vmcnt(0)" ::: "memory");
  __builtin_amdgcn_s_barrier();
  compute((NKV - 1) & 1);

  // ---- flash-combine the two kv-streams (waves w and w^1) ----
  __syncthreads();
  if (hi < 2) Msh[w][hi][q16] = make_float2(m_r[hi], l_r[hi]);
  __syncthreads();
  float invl[2], fown[2];
#pragma unroll
  for (int qf = 0; qf < 2; ++qf) {
    float2 pm = Msh[w ^ 1][qf][q16];
    float ms = fmaxf(m_r[qf], pm.x);
    fown[qf] = ex2(m_r[qf] - ms);
    float ls = l_r[qf] * fown[qf] + pm.y * ex2(pm.x - ms);
    invl[qf] = 1.0f / ls;
  }
#pragma unroll
  for (int ni = 0; ni < 8; ++ni) {
    acc[ni][0] *= fown[0];
    acc[ni][1] *= fown[1];
  }
  char* xch = (char*)&KV[0][0][0] + a * 17408 + lane * 272;
  if (b == 1) {
#pragma unroll
    for (int ni = 0; ni < 8; ++ni) {
      *(f32x4*)(xch + (ni * 2 + 0) * 16) = acc[ni][0];
      *(f32x4*)(xch + (ni * 2 + 1) * 16) = acc[ni][1];
    }
  }
  __syncthreads();
  if (b == 0) {
#pragma unroll
    for (int ni = 0; ni < 8; ++ni) {
#pragma unroll
      for (int qf = 0; qf < 2; ++qf) {
        f32x4 o = acc[ni][qf] + *(const f32x4*)(xch + (ni * 2 + qf) * 16);
        float il = invl[qf];
        uint2 pk;
        pk.x = cvtpk(o[0] * il, o[1] * il);
        pk.y = cvtpk(o[2] * il, o[3] * il);
        int qrow = qt * 64 + a * 32 + qf * 16 + q16;
        *(uint2*)(ab + (long)qrow * DIM + h * HD + 16 * ni + hi * 4) = pk;
      }
    }
  }
}

// ---------------------------------------------------------------------------
extern "C" void kernel_launch(void* const* d_in, const int* in_sizes, int n_in,
                              void* d_out, int out_size, void* d_ws, size_t ws_size,
                              hipStream_t stream) {
  const float* x     = (const float*)d_in[0];
  const float* freqs = (const float*)d_in[3];
  const float* Wq = (const float*)d_in[4];  const float* bq = (const float*)d_in[5];
  const float* Wk = (const float*)d_in[6];  const float* bk = (const float*)d_in[7];
  const float* Wv = (const float*)d_in[8];  const float* bv = (const float*)d_in[9];
  const float* Wo = (const float*)d_in[10]; const float* bo = (const float*)d_in[11];
  const float* gq = (const float*)d_in[12]; const float* gk = (const float*)d_in[13];

  char* ws = (char*)d_ws;
  size_t off = 0;
  auto alloc = [&](size_t bytes) -> char* {
    char* p = ws + off;
    off += (bytes + 255) & ~(size_t)255;
    return p;
  };
  ushort* xb   = (ushort*)alloc((size_t)MPAD * DIM * 2 + 4 * (size_t)DIM * DIM * 2);
  ushort* wall = xb + (size_t)MPAD * DIM;           // wq|wk|wv|wo
  ushort* wob  = wall + 3 * (size_t)DIM * DIM;
  ushort* qbb = (ushort*)alloc((size_t)LSEQ * DIM * 2);
  ushort* kbb = (ushort*)alloc((size_t)LSEQ * DIM * 2);
  ushort* vT  = (ushort*)alloc((size_t)DIM * LSEQ * 2);
  ushort* ab  = (ushort*)alloc((size_t)MPAD * DIM * 2);

  const long tot8 = ((long)MPAD * DIM + 4L * DIM * DIM) / 8;
  cast_all<<<(int)(tot8 / 256), 256, 0, stream>>>(x, Wq, Wk, Wv, Wo, xb);

  gemm_qkv<<<dim3(MPAD / 128, 36), 256, 0, stream>>>(xb, wall, bq, bk, bv, qbb, kbb, vT);

  postqk_kernel<<<dim3(LSEQ, 2), 256, 0, stream>>>(qbb, kbb, gq, gk, freqs);

  attn_kernel<<<dim3(NKV, HEADS), 256, 0, stream>>>(qbb, kbb, vT, ab);

  gemm_out<<<dim3(MPAD / 128, DIM / 128), 256, 0, stream>>>(ab, wob, bo, (float*)d_out);
}